// Round 6
// baseline (259.566 us; speedup 1.0000x reference)
//
#include <hip/hip_runtime.h>
#include <stdint.h>

// ksparse: per row of 4096x8192 f32, threshold = 513th largest value (k=512),
// out = x * (x > thresh). One block per row; exact MSB radix-select (4x8bit)
// on order-preserving uint32 mapping, data held in registers (single HBM read,
// single HBM write).

constexpr int COLS = 8192;
constexpr int TPB  = 256;
constexpr int EPT  = COLS / TPB;   // 32 elements per thread
constexpr int VPT  = EPT / 4;      // 8 float4 per thread
constexpr int HIST_STRIDE = 260;   // 256 bins + 4 pad words: staggers bank of
                                   // same bin across the 4 per-wave replicas

__device__ __forceinline__ uint32_t map_f32(uint32_t u) {
  // order-preserving map: unsigned compare == float compare
  return (u & 0x80000000u) ? ~u : (u | 0x80000000u);
}

__device__ __forceinline__ float unmap_f32(uint32_t m) {
  return __uint_as_float((m & 0x80000000u) ? (m ^ 0x80000000u) : ~m);
}

__global__ __launch_bounds__(TPB)
void ksparse_kernel(const float* __restrict__ in, const int* __restrict__ kptr,
                    float* __restrict__ out) {
  __shared__ uint32_t hist[4 * HIST_STRIDE]; // per-wave privatized histograms
  __shared__ uint32_t sscan[256];            // suffix counts per bin
  __shared__ uint32_t wtot[4];               // per-wave segment totals
  __shared__ int s_dmax;

  const int t    = threadIdx.x;
  const int wave = t >> 6;
  const int lane = t & 63;
  const size_t rowbase = (size_t)blockIdx.x * COLS;

  // ---- load row, map to sortable uints (registers only) ----
  uint32_t m[EPT];
  const float4* inp = (const float4*)(in + rowbase);
#pragma unroll
  for (int i = 0; i < VPT; ++i) {
    float4 v = inp[t + i * TPB];
    m[4 * i + 0] = map_f32(__float_as_uint(v.x));
    m[4 * i + 1] = map_f32(__float_as_uint(v.y));
    m[4 * i + 2] = map_f32(__float_as_uint(v.z));
    m[4 * i + 3] = map_f32(__float_as_uint(v.w));
  }

  uint32_t kk = (uint32_t)(*kptr) + 1u; // rank from top: 513th largest
  uint32_t prefix = 0;

#pragma unroll 1
  for (int pass = 0; pass < 4; ++pass) {
    const int shift = 24 - 8 * pass;

    // zero replicated histograms; re-init argmax
#pragma unroll
    for (int j = 0; j < 5; ++j) {
      int idx = t + j * TPB;
      if (idx < 4 * HIST_STRIDE) hist[idx] = 0u;
    }
    if (t == 0) s_dmax = -1;
    __syncthreads();

    const uint32_t hi_mask = (pass == 0) ? 0u : (0xFFFFFFFFu << (shift + 8));
    const uint32_t want    = (pass == 0) ? 0u : (prefix << (shift + 8));
    uint32_t* h = &hist[wave * HIST_STRIDE];
#pragma unroll
    for (int i = 0; i < EPT; ++i) {
      if ((m[i] & hi_mask) == want)
        atomicAdd(&h[(m[i] >> shift) & 255u], 1u);
    }
    __syncthreads();

    // merge the 4 replicas for this thread's bin
    uint32_t s = hist[t] + hist[HIST_STRIDE + t] +
                 hist[2 * HIST_STRIDE + t] + hist[3 * HIST_STRIDE + t];
    // wave-level suffix sum over the wave's 64-bin segment (no barriers)
#pragma unroll
    for (int off = 1; off < 64; off <<= 1) {
      uint32_t tmp = __shfl_down(s, off, 64);
      s += (lane + off < 64) ? tmp : 0u;
    }
    if (lane == 0) wtot[wave] = s;
    __syncthreads();

    uint32_t suff = s;
#pragma unroll
    for (int w = 1; w < 4; ++w)
      if (w > wave) suff += wtot[w];
    sscan[t] = suff; // suff = # candidates with digit >= t
    if (suff >= kk) atomicMax(&s_dmax, t);
    __syncthreads();

    const int d = s_dmax;                                 // threshold digit
    const uint32_t above = (d < 255) ? sscan[d + 1] : 0u; // strictly-above count
    kk -= above;
    prefix = (prefix << 8) | (uint32_t)d;
    __syncthreads(); // protect sscan/wtot/s_dmax before next-pass reuse
  }

  const uint32_t T = prefix; // exact mapped bits of the rank-(k+1) element

  // ---- masked write: keep strictly greater than threshold ----
  float4* op = (float4*)(out + rowbase);
#pragma unroll
  for (int i = 0; i < VPT; ++i) {
    float4 v;
    uint32_t mm;
    mm  = m[4 * i + 0]; v.x = (mm > T) ? unmap_f32(mm) : 0.0f;
    mm  = m[4 * i + 1]; v.y = (mm > T) ? unmap_f32(mm) : 0.0f;
    mm  = m[4 * i + 2]; v.z = (mm > T) ? unmap_f32(mm) : 0.0f;
    mm  = m[4 * i + 3]; v.w = (mm > T) ? unmap_f32(mm) : 0.0f;
    op[t + i * TPB] = v;
  }
}

extern "C" void kernel_launch(void* const* d_in, const int* in_sizes, int n_in,
                              void* d_out, int out_size, void* d_ws, size_t ws_size,
                              hipStream_t stream) {
  const float* in  = (const float*)d_in[0];
  const int*   k   = (const int*)d_in[1];
  float*       out = (float*)d_out;
  int rows = in_sizes[0] / COLS;
  if (rows < 1) rows = 1;
  ksparse_kernel<<<rows, TPB, 0, stream>>>(in, k, out);
}

// Round 7
// 240.069 us; speedup vs baseline: 1.0812x; 1.0812x over previous
//
#include <hip/hip_runtime.h>
#include <stdint.h>

// ksparse: per row of 4096x8192 f32, threshold = 513th largest (k=512),
// out = x * (x > thresh). One block per row. Exact MSB radix-select over the
// order-preserving uint32 mapping, 3 passes of 11/11/10 bits (2048-bin
// histograms spread the N(0,1) exponent hot-spot ~8x vs 8-bit digits,
// cutting LDS same-address atomic serialization). Data stays in registers:
// single HBM read + single HBM write.

constexpr int COLS = 8192;
constexpr int TPB  = 256;
constexpr int EPT  = COLS / TPB;   // 32 elements per thread
constexpr int VPT  = EPT / 4;      // 8 float4 per thread
constexpr int NBIN = 2048;         // 11-bit digits
constexpr int NREP = 2;            // histogram replicas (one per wave-pair)

__device__ __forceinline__ uint32_t map_f32(uint32_t u) {
  return (u & 0x80000000u) ? ~u : (u | 0x80000000u);
}
__device__ __forceinline__ float unmap_f32(uint32_t m) {
  return __uint_as_float((m & 0x80000000u) ? (m ^ 0x80000000u) : ~m);
}

__global__ __launch_bounds__(TPB)
void ksparse_kernel(const float* __restrict__ in, const int* __restrict__ kptr,
                    float* __restrict__ out) {
  __shared__ __align__(16) uint32_t hist[NREP * NBIN]; // 16 KiB
  __shared__ uint32_t wtot[4];
  __shared__ int s_dmax;
  __shared__ uint32_t s_above;

  const int t    = threadIdx.x;
  const int wave = t >> 6;
  const int lane = t & 63;
  const size_t rowbase = (size_t)blockIdx.x * COLS;

  // ---- load row, map to sortable uints (registers) ----
  uint32_t m[EPT];
  const float4* inp = (const float4*)(in + rowbase);
#pragma unroll
  for (int i = 0; i < VPT; ++i) {
    float4 v = inp[t + i * TPB];
    m[4 * i + 0] = map_f32(__float_as_uint(v.x));
    m[4 * i + 1] = map_f32(__float_as_uint(v.y));
    m[4 * i + 2] = map_f32(__float_as_uint(v.z));
    m[4 * i + 3] = map_f32(__float_as_uint(v.w));
  }

  uint32_t kk = (uint32_t)(*kptr) + 1u; // rank from top: 513th largest
  uint32_t pref = 0;

  const int shifts[3]  = {21, 10, 0};      // digit position
  const int dmask[3]   = {0x7FF, 0x7FF, 0x3FF};
  const int cshifts[3] = {0, 21, 10};      // candidate-prefix compare shift

#pragma unroll 1
  for (int pass = 0; pass < 3; ++pass) {
    const int shift = shifts[pass];
    const uint32_t dm = (uint32_t)dmask[pass];

    // zero histogram (16B vector stores), reset digit argmax
    uint4* h4 = (uint4*)hist;
#pragma unroll
    for (int i = 0; i < (NREP * NBIN / 4) / TPB; ++i)
      h4[t + i * TPB] = make_uint4(0u, 0u, 0u, 0u);
    if (t == 0) s_dmax = -1;
    __syncthreads(); // A

    uint32_t* h = &hist[(wave >> 1) * NBIN];
    if (pass == 0) {
#pragma unroll
      for (int i = 0; i < EPT; ++i)
        atomicAdd(&h[m[i] >> 21], 1u);
    } else {
      const int cs = cshifts[pass];
#pragma unroll
      for (int i = 0; i < EPT; ++i) {
        if ((m[i] >> cs) == pref)
          atomicAdd(&h[(m[i] >> shift) & dm], 1u);
      }
    }
    __syncthreads(); // B

    // ---- hierarchical suffix scan over NBIN bins; 8 bins/thread ----
    const uint4* hv = (const uint4*)hist;
    uint4 a0 = hv[2 * t];
    uint4 a1 = hv[2 * t + 1];
    uint4 b0 = hv[NBIN / 4 + 2 * t];
    uint4 b1 = hv[NBIN / 4 + 2 * t + 1];
    uint32_t c0 = a0.x + b0.x, c1 = a0.y + b0.y, c2 = a0.z + b0.z, c3 = a0.w + b0.w;
    uint32_t c4 = a1.x + b1.x, c5 = a1.y + b1.y, c6 = a1.z + b1.z, c7 = a1.w + b1.w;
    uint32_t sl[8];
    sl[7] = c7;       sl[6] = sl[7] + c6; sl[5] = sl[6] + c5; sl[4] = sl[5] + c4;
    sl[3] = sl[4] + c3; sl[2] = sl[3] + c2; sl[1] = sl[2] + c1; sl[0] = sl[1] + c0;
    const uint32_t total = sl[0];

    uint32_t s = total; // wave-inclusive suffix of per-thread totals
#pragma unroll
    for (int off = 1; off < 64; off <<= 1) {
      uint32_t tmp = __shfl_down(s, off, 64);
      s += (lane + off < 64) ? tmp : 0u;
    }
    if (lane == 0) wtot[wave] = s;
    __syncthreads(); // C

    uint32_t hi = 0;
#pragma unroll
    for (int w = 1; w < 4; ++w)
      if (w > wave) hi += wtot[w];
    const uint32_t excl = hi + (s - total); // suffix strictly after my 8 bins

    // largest owned bin with suffix >= kk
    int best = -1;
#pragma unroll
    for (int j = 7; j >= 0; --j) {
      if (best < 0 && excl + sl[j] >= kk) best = j;
    }
    if (best >= 0) atomicMax(&s_dmax, t * 8 + best);
    __syncthreads(); // D

    const int d = s_dmax;
    if (t == (d >> 3)) {
      const int j = d & 7;
      s_above = excl + ((j < 7) ? sl[j + 1] : 0u); // count strictly above bin d
    }
    __syncthreads(); // E

    kk -= s_above;
    pref = (pass == 0) ? (uint32_t)d
                       : ((pref << ((pass == 2) ? 10 : 11)) | (uint32_t)d);
    __syncthreads(); // protect s_above/s_dmax before next-pass reset
  }

  const uint32_t T = pref; // exact mapped bits of the rank-(k+1) element

  // ---- masked write: keep strictly greater than threshold ----
  float4* op = (float4*)(out + rowbase);
#pragma unroll
  for (int i = 0; i < VPT; ++i) {
    float4 v;
    uint32_t mm;
    mm  = m[4 * i + 0]; v.x = (mm > T) ? unmap_f32(mm) : 0.0f;
    mm  = m[4 * i + 1]; v.y = (mm > T) ? unmap_f32(mm) : 0.0f;
    mm  = m[4 * i + 2]; v.z = (mm > T) ? unmap_f32(mm) : 0.0f;
    mm  = m[4 * i + 3]; v.w = (mm > T) ? unmap_f32(mm) : 0.0f;
    op[t + i * TPB] = v;
  }
}

extern "C" void kernel_launch(void* const* d_in, const int* in_sizes, int n_in,
                              void* d_out, int out_size, void* d_ws, size_t ws_size,
                              hipStream_t stream) {
  const float* in  = (const float*)d_in[0];
  const int*   k   = (const int*)d_in[1];
  float*       out = (float*)d_out;
  int rows = in_sizes[0] / COLS;
  if (rows < 1) rows = 1;
  ksparse_kernel<<<rows, TPB, 0, stream>>>(in, k, out);
}

// Round 8
// 235.119 us; speedup vs baseline: 1.1040x; 1.0211x over previous
//
#include <hip/hip_runtime.h>
#include <stdint.h>

// ksparse: per row of 4096x8192 f32, threshold = 513th largest (k=512),
// out = x * (x > thresh). One block per row. Exact radix-select on the
// order-preserving uint32 mapping: ONE 11-bit/2048-bin pass over all 8192
// elements, then candidate compaction (~220 survivors) into LDS, then three
// 7-bit/128-bin tail passes scanned by a single wave (ballot+clz, 2 barriers
// each). Data stays in registers: single HBM read + single HBM write.

constexpr int COLS  = 8192;
constexpr int TPB   = 256;
constexpr int EPT   = COLS / TPB;  // 32 elements per thread
constexpr int VPT   = EPT / 4;     // 8 float4 per thread
constexpr int NBIN0 = 2048;        // pass-0 bins (11 bits)
constexpr int CAP   = 2048;        // candidate buffer capacity (reuses replica 1)

__device__ __forceinline__ uint32_t map_f32(uint32_t u) {
  return (u & 0x80000000u) ? ~u : (u | 0x80000000u);
}
__device__ __forceinline__ float unmap_f32(uint32_t m) {
  return __uint_as_float((m & 0x80000000u) ? (m ^ 0x80000000u) : ~m);
}

__global__ __launch_bounds__(TPB)
void ksparse_kernel(const float* __restrict__ in, const int* __restrict__ kptr,
                    float* __restrict__ out) {
  __shared__ __align__(16) uint32_t hist[2 * NBIN0]; // 16 KiB: replica0 | replica1 (-> cand)
  __shared__ uint32_t th[3 * 128];                   // tail histograms, zeroed up-front
  __shared__ uint32_t wtot[4];
  __shared__ uint32_t s_packed;                      // (bin<<14)|above from pass 0
  __shared__ uint32_t s_cnt;                         // candidate count
  __shared__ uint32_t s_sel[3];                      // (digit<<16)|above per tail pass

  const int t    = threadIdx.x;
  const int wave = t >> 6;
  const int lane = t & 63;
  const size_t rowbase = (size_t)blockIdx.x * COLS;

  // ---- issue all global loads first; LDS zeroing overlaps their latency ----
  const float4* inp = (const float4*)(in + rowbase);
  float4 v[VPT];
#pragma unroll
  for (int i = 0; i < VPT; ++i) v[i] = inp[t + i * TPB];

  uint4* h4 = (uint4*)hist;
#pragma unroll
  for (int i = 0; i < 4; ++i) h4[t + i * TPB] = make_uint4(0u, 0u, 0u, 0u);
  th[t] = 0u;
  if (t < 128) th[256 + t] = 0u;
  if (t == 0) { s_packed = 0u; s_cnt = 0u; }
  uint32_t kk = (uint32_t)(*kptr) + 1u; // rank from top: 513th largest
  __syncthreads(); // B1: zeroing done

  // ---- pass 0: map + 2048-bin histogram (2 replicas, one per wave-pair) ----
  uint32_t m[EPT];
  uint32_t* h = &hist[(wave >> 1) * NBIN0];
#pragma unroll
  for (int i = 0; i < VPT; ++i) {
    m[4 * i + 0] = map_f32(__float_as_uint(v[i].x));
    m[4 * i + 1] = map_f32(__float_as_uint(v[i].y));
    m[4 * i + 2] = map_f32(__float_as_uint(v[i].z));
    m[4 * i + 3] = map_f32(__float_as_uint(v[i].w));
    atomicAdd(&h[m[4 * i + 0] >> 21], 1u);
    atomicAdd(&h[m[4 * i + 1] >> 21], 1u);
    atomicAdd(&h[m[4 * i + 2] >> 21], 1u);
    atomicAdd(&h[m[4 * i + 3] >> 21], 1u);
  }
  __syncthreads(); // B2: histogram done

  // ---- pass-0 scan: 8 bins/thread, wave suffix, packed argmax ----
  {
    const uint4* hv = (const uint4*)hist;
    uint4 a0 = hv[2 * t], a1 = hv[2 * t + 1];
    uint4 b0 = hv[512 + 2 * t], b1 = hv[512 + 2 * t + 1];
    uint32_t c0 = a0.x + b0.x, c1 = a0.y + b0.y, c2 = a0.z + b0.z, c3 = a0.w + b0.w;
    uint32_t c4 = a1.x + b1.x, c5 = a1.y + b1.y, c6 = a1.z + b1.z, c7 = a1.w + b1.w;
    uint32_t sl[8];
    sl[7] = c7;         sl[6] = sl[7] + c6; sl[5] = sl[6] + c5; sl[4] = sl[5] + c4;
    sl[3] = sl[4] + c3; sl[2] = sl[3] + c2; sl[1] = sl[2] + c1; sl[0] = sl[1] + c0;
    const uint32_t total = sl[0];

    uint32_t s = total;
#pragma unroll
    for (int off = 1; off < 64; off <<= 1) {
      uint32_t tmp = __shfl_down(s, off, 64);
      s += (lane + off < 64) ? tmp : 0u;
    }
    if (lane == 0) wtot[wave] = s;
    __syncthreads(); // B3

    uint32_t hi = 0;
#pragma unroll
    for (int w = 1; w < 4; ++w)
      if (w > wave) hi += wtot[w];
    const uint32_t excl = hi + (s - total);

    int best = -1;
#pragma unroll
    for (int j = 7; j >= 0; --j)
      if (best < 0 && excl + sl[j] >= kk) best = j;
    if (best >= 0) {
      const uint32_t above = excl + ((best < 7) ? sl[best + 1] : 0u);
      atomicMax(&s_packed, ((uint32_t)(t * 8 + best) << 14) | above);
    }
  }
  __syncthreads(); // B4

  const uint32_t pk = s_packed;
  const uint32_t d0 = pk >> 14;
  kk -= (pk & 0x3FFFu);

  // ---- compact candidates (top-11 bits == d0) into dead replica-1 LDS ----
  uint32_t* cand = &hist[NBIN0];
#pragma unroll
  for (int i = 0; i < EPT; ++i) {
    if ((m[i] >> 21) == d0) {
      uint32_t idx = atomicAdd(&s_cnt, 1u);
      if (idx < CAP) cand[idx] = m[i] & 0x1FFFFFu; // low 21 bits
    }
  }
  __syncthreads(); // B5
  const uint32_t Cc = (s_cnt < (uint32_t)CAP) ? s_cnt : (uint32_t)CAP;

  // ---- three 7-bit tail passes over the candidates ----
  uint32_t tpref = 0;
#pragma unroll 1
  for (int j = 0; j < 3; ++j) {
    const int dsh = 14 - 7 * j;
    uint32_t* thj = &th[j * 128];
    for (uint32_t idx = t; idx < Cc; idx += TPB) {
      const uint32_t c = cand[idx];
      const bool ok = (j == 0) || ((c >> (dsh + 7)) == tpref);
      if (ok) atomicAdd(&thj[(c >> dsh) & 127u], 1u);
    }
    __syncthreads(); // tail histogram done

    if (wave == 0) { // single-wave 128-bin suffix scan + digit pick
      uint32_t a = thj[lane], b = thj[64 + lane];
      uint32_t sb = b, sa = a;
#pragma unroll
      for (int off = 1; off < 64; off <<= 1) {
        uint32_t t1 = __shfl_down(sb, off, 64);
        uint32_t t2 = __shfl_down(sa, off, 64);
        const bool inr = (lane + off < 64);
        sb += inr ? t1 : 0u;
        sa += inr ? t2 : 0u;
      }
      const uint32_t tb = __shfl(sb, 0, 64); // total of bins 64..127
      sa += tb;
      const unsigned long long mb = __ballot(sb >= kk);
      uint32_t d, ab;
      if (mb) {
        const int hb = 63 - __builtin_clzll(mb);
        const uint32_t nx = __shfl(sb, (hb + 1) & 63, 64);
        d = 64 + hb;
        ab = (hb == 63) ? 0u : nx;
      } else {
        const unsigned long long ma = __ballot(sa >= kk); // nonzero by invariant
        const int ha = 63 - __builtin_clzll(ma);
        const uint32_t nx = __shfl(sa, (ha + 1) & 63, 64);
        d = (uint32_t)ha;
        ab = (ha == 63) ? tb : nx;
      }
      if (lane == 0) s_sel[j] = (d << 16) | ab;
    }
    __syncthreads(); // selection published

    const uint32_t sel = s_sel[j];
    tpref = (tpref << 7) | (sel >> 16);
    kk -= (sel & 0xFFFFu);
  }

  const uint32_t T = (d0 << 21) | tpref; // exact mapped bits of rank-(k+1) elem

  // ---- masked write: keep strictly greater than threshold ----
  float4* op = (float4*)(out + rowbase);
#pragma unroll
  for (int i = 0; i < VPT; ++i) {
    float4 w;
    uint32_t mm;
    mm = m[4 * i + 0]; w.x = (mm > T) ? unmap_f32(mm) : 0.0f;
    mm = m[4 * i + 1]; w.y = (mm > T) ? unmap_f32(mm) : 0.0f;
    mm = m[4 * i + 2]; w.z = (mm > T) ? unmap_f32(mm) : 0.0f;
    mm = m[4 * i + 3]; w.w = (mm > T) ? unmap_f32(mm) : 0.0f;
    op[t + i * TPB] = w;
  }
}

extern "C" void kernel_launch(void* const* d_in, const int* in_sizes, int n_in,
                              void* d_out, int out_size, void* d_ws, size_t ws_size,
                              hipStream_t stream) {
  const float* in  = (const float*)d_in[0];
  const int*   k   = (const int*)d_in[1];
  float*       out = (float*)d_out;
  int rows = in_sizes[0] / COLS;
  if (rows < 1) rows = 1;
  ksparse_kernel<<<rows, TPB, 0, stream>>>(in, k, out);
}